// Round 6
// baseline (478.521 us; speedup 1.0000x reference)
//
#include <hip/hip_runtime.h>
#include <hip/hip_bf16.h>

// TreeLSTM on MI355X — MFMA formulation, round 6.
// 128 trees, heap layout, TREE_SIZE=511, depth 9; children of heap h: 2h+1, 2h+2.
// Gates GEMM per node: A-row = [x | h0+h1 | h0 | h1] (K=512) @ B (512x640),
// col blocks [i|o|u|f0|f1]. B is 50% structural zeros -> packed as 4 segments:
//   seg0: kb 0-3  (x)    -> cols 0-639   (Wi + Wf + Wf)
//   seg1: kb 4-7  (hsum) -> cols 0-383   (Ui)
//   seg2: kb 8-11 (h0)   -> cols 384-511 (Uf)
//   seg3: kb 12-15(h1)   -> cols 512-639 (Uf)
// d=8 leaves + d=7..5 via gemm_level (d=5 writes compact per-layer stash);
// one merged tail dispatch (256 blocks = layer x tree) does d=4..0 with h/c in LDS.

#define TS 511
#define NT 128
#define NN (NT * TS)   // 65408
#define LAYB 163840    // Bg2 elements per layer

typedef __attribute__((ext_vector_type(8))) short short8;
typedef __attribute__((ext_vector_type(4))) short short4v;
typedef __attribute__((ext_vector_type(4))) float floatx4;

__device__ __forceinline__ unsigned short f2b(float f) {
    return __builtin_bit_cast(unsigned short, __float2bfloat16(f));
}
__device__ __forceinline__ float b2f_u(unsigned short u) {
    unsigned v = (unsigned)u << 16;
    return __builtin_bit_cast(float, v);
}
__device__ __forceinline__ float sig_(float x) { return 1.0f / (1.0f + __expf(-x)); }
__device__ __forceinline__ float tanh_(float x) {
    float a = fabsf(x);
    float t = __expf(-2.0f * a);
    float r = (1.0f - t) / (1.0f + t);
    return copysignf(r, x);
}

// ---------------- weight packing (segmented, zero blocks dropped) ----------------
// seg layout within layer: [kbl][col - colbase][32 k']
__global__ void pack_b(const float* __restrict__ Wiou, const float* __restrict__ biou,
                       const float* __restrict__ Uiou, const float* __restrict__ Wf,
                       const float* __restrict__ bfv, const float* __restrict__ Uf,
                       unsigned short* __restrict__ Bg, float* __restrict__ bp5) {
    int tid = blockIdx.x * 256 + threadIdx.x;   // 0..327679
    if (tid < 1280) {
        int l = tid / 640, r = tid % 640, g = r >> 7, o = r & 127;
        bp5[tid] = (g < 3) ? biou[l * 384 + r] : bfv[l * 128 + o];
    }
    int l = tid / LAYB;
    int e = tid % LAYB;
    int kb, col, kp;
    if (e < 81920)        { kb = e / 20480;            int r = e % 20480; col = r >> 5;         kp = r & 31; }
    else if (e < 131072)  { int e2 = e - 81920;  kb = 4  + e2 / 12288; int r = e2 % 12288; col = r >> 5;         kp = r & 31; }
    else if (e < 147456)  { int e3 = e - 131072; kb = 8  + e3 / 4096;  int r = e3 % 4096;  col = 384 + (r >> 5); kp = r & 31; }
    else                  { int e4 = e - 147456; kb = 12 + e4 / 4096;  int r = e4 % 4096;  col = 512 + (r >> 5); kp = r & 31; }
    int k = kb * 32 + kp;
    float v;
    if (k < 128) {
        if (col < 384)      v = Wiou[(l * 384 + col) * 128 + k];
        else if (col < 512) v = Wf[(l * 128 + col - 384) * 128 + k];
        else                v = Wf[(l * 128 + col - 512) * 128 + k];
    } else if (k < 256) {
        v = Uiou[(l * 384 + col) * 128 + (k - 128)];
    } else if (k < 384) {
        v = Uf[(l * 128 + (col - 384)) * 128 + (k - 256)];
    } else {
        v = Uf[(l * 128 + (col - 512)) * 128 + (k - 384)];
    }
    Bg[(size_t)l * LAYB + e] = f2b(v);
}

// ---------------- MFMA level GEMM (d=8..5) ----------------
// Block: 64 nodes x NCOLS. 512 threads = 8 waves (2 M-groups x 4 N-groups).
// COMPACT: write h/c to stash at j*128 (d=5 -> tail input).
template <int NKB, int NCOLS, bool LEAF, bool COMPACT>
__global__ __launch_bounds__(512) void gemm_level(
        const float* __restrict__ feat, const unsigned short* __restrict__ Bg,
        const float* __restrict__ bp5, unsigned short* __restrict__ h,
        unsigned short* __restrict__ c, unsigned short* __restrict__ hout,
        unsigned short* __restrict__ cout, int l, int d) {
    constexpr int NI = NCOLS / 64;
    constexpr int BS_BYTES = NCOLS * 40 * 2;
    constexpr int LG_BYTES = 32 * 656 * 2;
    __shared__ char smem[5120 + (BS_BYTES > LG_BYTES ? BS_BYTES : LG_BYTES)];
    unsigned short* As = (unsigned short*)smem;
    unsigned short* Bs = (unsigned short*)(smem + 5120);
    unsigned short* Lg = (unsigned short*)(smem + 5120);

    const int tid = threadIdx.x;
    const int lane = tid & 63, wave = tid >> 6;
    const int wm = wave & 1, wn = wave >> 1;
    const int quad = lane >> 4, l15 = lane & 15;
    const unsigned short* Bl = Bg + (size_t)l * LAYB;

    const int s = tid & 7, nl_st = tid >> 3;
    const int j_st = blockIdx.x * 64 + nl_st;
    int node_st, ch0_st = 0;
    if (LEAF) {
        node_st = (j_st >> 8) * TS + 255 + (j_st & 255);
    } else {
        int tree = j_st >> d, idx = j_st & ((1 << d) - 1);
        int heap = (1 << d) - 1 + idx;
        node_st = tree * TS + heap;
        ch0_st = tree * TS + 2 * heap + 1;
    }

    floatx4 acc[2][NI];
#pragma unroll
    for (int mi = 0; mi < 2; mi++)
#pragma unroll
        for (int ni = 0; ni < NI; ni++)
            acc[mi][ni] = (floatx4){0.f, 0.f, 0.f, 0.f};

    for (int kb = 0; kb < NKB; kb++) {
        int p = kb >> 2, kbl = kb & 3;
        int cb, ncol, segoff;
        if (LEAF) { cb = 0; ncol = 384; segoff = kb * 20480; kbl = 0; }
        else {
            cb     = (p == 0) ? 0 : (p == 1) ? 0 : (p == 2) ? 384 : 512;
            ncol   = (p == 0) ? 640 : (p == 1) ? 384 : 128;
            segoff = (p == 0) ? 0 : (p == 1) ? 81920 : (p == 2) ? 131072 : 147456;
            segoff += kbl * ncol * 32;
        }
        const int ce = cb + ncol;
        const unsigned short* Bsrc = Bl + segoff;
        __syncthreads();
        int nch = ncol * 4;
        for (int i = tid; i < nch; i += 512) {
            int n = i >> 2, part = i & 3;
            *(int4*)(Bs + n * 40 + part * 8) = *(const int4*)(Bsrc + (size_t)n * 32 + part * 8);
        }
        if (LEAF || kb < 4) {
            float4 xv = *(const float4*)(feat + (size_t)node_st * 128 + kb * 32 + s * 4);
            short4v r;
            r[0] = (short)f2b(xv.x); r[1] = (short)f2b(xv.y);
            r[2] = (short)f2b(xv.z); r[3] = (short)f2b(xv.w);
            *(short4v*)(As + nl_st * 40 + s * 4) = r;
        } else if (kb < 8) {
            int k0 = (kb - 4) * 32 + s * 4;
            short4v a = *(const short4v*)(h + (size_t)ch0_st * 128 + k0);
            short4v b = *(const short4v*)(h + (size_t)(ch0_st + 1) * 128 + k0);
            short4v r;
#pragma unroll
            for (int e = 0; e < 4; e++)
                r[e] = (short)f2b(b2f_u((unsigned short)a[e]) + b2f_u((unsigned short)b[e]));
            *(short4v*)(As + nl_st * 40 + s * 4) = r;
        } else if (kb < 12) {
            int k0 = (kb - 8) * 32 + s * 4;
            *(short4v*)(As + nl_st * 40 + s * 4) =
                *(const short4v*)(h + (size_t)ch0_st * 128 + k0);
        } else {
            int k0 = (kb - 12) * 32 + s * 4;
            *(short4v*)(As + nl_st * 40 + s * 4) =
                *(const short4v*)(h + (size_t)(ch0_st + 1) * 128 + k0);
        }
        __syncthreads();
        short8 a0 = *(const short8*)(As + (wm * 32 + l15) * 40 + quad * 8);
        short8 a1 = *(const short8*)(As + (wm * 32 + 16 + l15) * 40 + quad * 8);
#pragma unroll
        for (int ni = 0; ni < NI; ni++) {
            int gc0 = wn * (NCOLS / 4) + ni * 16;
            if (LEAF || (gc0 >= cb && gc0 < ce)) {
                short8 b = *(const short8*)(Bs + (gc0 - (LEAF ? 0 : cb) + l15) * 40 + quad * 8);
                acc[0][ni] = __builtin_amdgcn_mfma_f32_16x16x32_bf16(a0, b, acc[0][ni], 0, 0, 0);
                acc[1][ni] = __builtin_amdgcn_mfma_f32_16x16x32_bf16(a1, b, acc[1][ni], 0, 0, 0);
            }
        }
    }

    const int nl_ep = tid >> 4;
    const int t0 = (tid & 15) * 8;
    for (int half = 0; half < 2; half++) {
        __syncthreads();
        if (wm == half) {
#pragma unroll
            for (int mi = 0; mi < 2; mi++)
#pragma unroll
                for (int ni = 0; ni < NI; ni++)
#pragma unroll
                    for (int r = 0; r < 4; r++) {
                        int row = mi * 16 + quad * 4 + r;
                        int col = wn * (NCOLS / 4) + ni * 16 + l15;
                        Lg[row * 656 + col] = f2b(acc[mi][ni][r]);
                    }
        }
        __syncthreads();
        int j = blockIdx.x * 64 + half * 32 + nl_ep;
        int node, ch0 = 0;
        if (LEAF) {
            node = (j >> 8) * TS + 255 + (j & 255);
        } else {
            int tree = j >> d, idx = j & ((1 << d) - 1);
            int heap = (1 << d) - 1 + idx;
            node = tree * TS + heap;
            ch0 = tree * TS + 2 * heap + 1;
        }
        const unsigned short* Lr = Lg + nl_ep * 656 + t0;
        short8 gI = *(const short8*)(Lr);
        short8 gO = *(const short8*)(Lr + 128);
        short8 gU = *(const short8*)(Lr + 256);
        const float* bb = bp5 + (size_t)l * 640 + t0;
        short8 hr, cr;
        if (LEAF) {
#pragma unroll
            for (int e = 0; e < 8; e++) {
                float iv = sig_(b2f_u((unsigned short)gI[e]) + bb[e]);
                float ov = sig_(b2f_u((unsigned short)gO[e]) + bb[128 + e]);
                float uv = tanh_(b2f_u((unsigned short)gU[e]) + bb[256 + e]);
                float cn = iv * uv;
                float hn = ov * tanh_(cn);
                hr[e] = (short)f2b(hn);
                cr[e] = (short)f2b(cn);
            }
        } else {
            short8 gF0 = *(const short8*)(Lr + 384);
            short8 gF1 = *(const short8*)(Lr + 512);
            short8 c0 = *(const short8*)(c + (size_t)ch0 * 128 + t0);
            short8 c1 = *(const short8*)(c + (size_t)(ch0 + 1) * 128 + t0);
#pragma unroll
            for (int e = 0; e < 8; e++) {
                float iv = sig_(b2f_u((unsigned short)gI[e]) + bb[e]);
                float ov = sig_(b2f_u((unsigned short)gO[e]) + bb[128 + e]);
                float uv = tanh_(b2f_u((unsigned short)gU[e]) + bb[256 + e]);
                float f0 = sig_(b2f_u((unsigned short)gF0[e]) + bb[384 + e]);
                float f1 = sig_(b2f_u((unsigned short)gF1[e]) + bb[512 + e]);
                float cn = iv * uv + f0 * b2f_u((unsigned short)c0[e])
                                   + f1 * b2f_u((unsigned short)c1[e]);
                float hn = ov * tanh_(cn);
                hr[e] = (short)f2b(hn);
                cr[e] = (short)f2b(cn);
            }
        }
        size_t base = COMPACT ? (size_t)j * 128 : (size_t)node * 128;
        *(short8*)(hout + base + t0) = hr;
        *(short8*)(cout + base + t0) = cr;
    }
}

// ---------------- merged MFMA tail: d=4..0 + root out ----------------
// 256 blocks = (layer, tree). 8 waves x 5 n-tiles (80 cols each).
// x staged once; tail h/c in LDS cache read directly as A-fragments.
// B-frags direct from global Bg2 (L2-resident), zero segments skipped.
__global__ __launch_bounds__(512) void tail_mfma(
        const float* __restrict__ feat, const unsigned short* __restrict__ Bg,
        const float* __restrict__ bp5, const unsigned short* __restrict__ sh,
        const unsigned short* __restrict__ sc, float* __restrict__ out) {
    __shared__ unsigned short xb[31 * 136];
    __shared__ unsigned short hcH[63 * 136];
    __shared__ unsigned short hcC[63 * 136];
    __shared__ unsigned short Lg[16 * 660];

    const int tid = threadIdx.x;
    const int l = blockIdx.x >> 7, tree = blockIdx.x & 127;
    const int lane = tid & 63, w = tid >> 6;
    const int quad = lane >> 4, l15 = lane & 15;
    const unsigned short* Bl = Bg + (size_t)l * LAYB;
    const float* bb = bp5 + (size_t)l * 640;

    // startup: stage x rows (heaps 0..30) and d=5 stash (heaps 31..62)
    {
        int row = tid >> 4, c8 = (tid & 15) * 8;
        if (row < 31) {
            const float* src = feat + ((size_t)tree * TS + row) * 128 + c8;
            short8 r;
#pragma unroll
            for (int e = 0; e < 8; e++) r[e] = (short)f2b(src[e]);
            *(short8*)(xb + row * 136 + c8) = r;
        }
        const unsigned short* hsrc = sh + ((size_t)(l * 128 + tree) * 32) * 128;
        const unsigned short* csrc = sc + ((size_t)(l * 128 + tree) * 32) * 128;
        *(short8*)(hcH + (31 + row) * 136 + c8) = *(const short8*)(hsrc + row * 128 + c8);
        *(short8*)(hcC + (31 + row) * 136 + c8) = *(const short8*)(csrc + row * 128 + c8);
    }
    __syncthreads();

    for (int dd = 4; dd >= 0; dd--) {
        const int nd = 1 << dd;
        const int row = (l15 < nd) ? l15 : nd - 1;   // clamp; rows >= nd produce unused garbage
        const int heap = nd - 1 + row;
        floatx4 acc[5];
#pragma unroll
        for (int ni = 0; ni < 5; ni++) acc[ni] = (floatx4){0.f, 0.f, 0.f, 0.f};
#pragma unroll
        for (int p = 0; p < 4; p++) {
            const int cb     = (p == 0) ? 0 : (p == 1) ? 0 : (p == 2) ? 384 : 512;
            const int ncol   = (p == 0) ? 640 : (p == 1) ? 384 : 128;
            const int so     = (p == 0) ? 0 : (p == 1) ? 81920 : (p == 2) ? 131072 : 147456;
            const int ce = cb + ncol;
#pragma unroll
            for (int kbl = 0; kbl < 4; kbl++) {
                const int ko = kbl * 32 + quad * 8;
                short8 a;
                if (p == 0) {
                    a = *(const short8*)(xb + heap * 136 + ko);
                } else if (p == 1) {
                    short8 x0 = *(const short8*)(hcH + (2 * heap + 1) * 136 + ko);
                    short8 x1 = *(const short8*)(hcH + (2 * heap + 2) * 136 + ko);
#pragma unroll
                    for (int e = 0; e < 8; e++)
                        a[e] = (short)f2b(b2f_u((unsigned short)x0[e]) +
                                          b2f_u((unsigned short)x1[e]));
                } else if (p == 2) {
                    a = *(const short8*)(hcH + (2 * heap + 1) * 136 + ko);
                } else {
                    a = *(const short8*)(hcH + (2 * heap + 2) * 136 + ko);
                }
#pragma unroll
                for (int ni = 0; ni < 5; ni++) {
                    int gc0 = (w * 5 + ni) * 16;
                    if (gc0 >= cb && gc0 < ce) {
                        const unsigned short* bp_ =
                            Bl + so + ((size_t)(kbl * ncol + gc0 - cb + l15)) * 32 + quad * 8;
                        short8 b = *(const short8*)bp_;
                        acc[ni] = __builtin_amdgcn_mfma_f32_16x16x32_bf16(a, b, acc[ni], 0, 0, 0);
                    }
                }
            }
        }
        __syncthreads();
#pragma unroll
        for (int ni = 0; ni < 5; ni++)
#pragma unroll
            for (int r = 0; r < 4; r++)
                Lg[(quad * 4 + r) * 660 + (w * 5 + ni) * 16 + l15] = f2b(acc[ni][r]);
        __syncthreads();
        for (int idx = tid; idx < nd * 128; idx += 512) {
            int node = idx >> 7, t = idx & 127;
            int hp = nd - 1 + node;
            const unsigned short* Lr = Lg + node * 660;
            float iv = sig_(b2f_u(Lr[t]) + bb[t]);
            float ov = sig_(b2f_u(Lr[128 + t]) + bb[128 + t]);
            float uv = tanh_(b2f_u(Lr[256 + t]) + bb[256 + t]);
            float f0 = sig_(b2f_u(Lr[384 + t]) + bb[384 + t]);
            float f1 = sig_(b2f_u(Lr[512 + t]) + bb[512 + t]);
            float c0v = b2f_u(hcC[(2 * hp + 1) * 136 + t]);
            float c1v = b2f_u(hcC[(2 * hp + 2) * 136 + t]);
            float cn = iv * uv + f0 * c0v + f1 * c1v;
            float hn = ov * tanh_(cn);
            hcH[hp * 136 + t] = f2b(hn);
            hcC[hp * 136 + t] = f2b(cn);
            if (dd == 0) {
                out[((size_t)l * 128 + tree) * 128 + t] = hn;
                out[32768 + ((size_t)l * 128 + tree) * 128 + t] = cn;
            }
        }
        __syncthreads();
    }
}

extern "C" void kernel_launch(void* const* d_in, const int* in_sizes, int n_in,
                              void* d_out, int out_size, void* d_ws, size_t ws_size,
                              hipStream_t stream) {
    const float* feat = (const float*)d_in[0];
    const float* Wiou = (const float*)d_in[1];
    const float* biou = (const float*)d_in[2];
    const float* Uiou = (const float*)d_in[3];
    const float* Wf   = (const float*)d_in[4];
    const float* bfv  = (const float*)d_in[5];
    const float* Uf   = (const float*)d_in[6];
    float* out = (float*)d_out;

    // ws: h,c bf16[NN*128] | stash h,c bf16[2*4096*128] | Bg2 bf16[2*LAYB] | bp5 f32
    // total ~38.3 MB
    unsigned short* h  = (unsigned short*)d_ws;
    unsigned short* c  = h + (size_t)NN * 128;
    unsigned short* sh = c + (size_t)NN * 128;
    unsigned short* sc = sh + (size_t)2 * 4096 * 128;
    unsigned short* Bg = sc + (size_t)2 * 4096 * 128;
    float* bp5 = (float*)(Bg + (size_t)2 * LAYB);

    pack_b<<<1280, 256, 0, stream>>>(Wiou, biou, Uiou, Wf, bfv, Uf, Bg, bp5);

    for (int l = 0; l < 2; l++) {
        gemm_level<4, 384, true, false><<<512, 512, 0, stream>>>(
            feat, Bg, bp5, h, c, h, c, l, 0);
        for (int d = 7; d >= 6; d--)
            gemm_level<16, 640, false, false><<<(2 << d), 512, 0, stream>>>(
                feat, Bg, bp5, h, c, h, c, l, d);
        gemm_level<16, 640, false, true><<<64, 512, 0, stream>>>(
            feat, Bg, bp5, h, c, sh + (size_t)l * 4096 * 128, sc + (size_t)l * 4096 * 128,
            l, 5);
    }
    tail_mfma<<<256, 512, 0, stream>>>(feat, Bg, bp5, sh, sc, out);
}

// Round 9
// 326.725 us; speedup vs baseline: 1.4646x; 1.4646x over previous
//
#include <hip/hip_runtime.h>
#include <hip/hip_bf16.h>

// TreeLSTM on MI355X — MFMA formulation, round 9.
// 128 trees, heap layout, TREE_SIZE=511, depth 9; children of heap h: 2h+1, 2h+2.
// Gates: A-row = [x | h0+h1 | h0 | h1] (K=512) @ B (512x640), col blocks [i|o|u|f0|f1].
// d=8 leaf + d=7..5 via gemm_level. Layer hazard fix (R8 bug): layer 1's d=5
//   output is redirected to dead heaps 255..286 (its leaf region, dead after d7),
//   so layer 0's d=5 results at natural heaps 31..62 survive until the merged tail.
// Tail (d=4..0): per-(layer,tree) block; B x-part AND U-part register-resident
//   (f0/f1 share Wf/Uf via col-128 alias), x + h/c in LDS, 2 barriers/level.
// ws ~35.3 MB (proven-safe size; R7's 49.8 MB overflowed d_ws).

#define TS 511
#define NT 128
#define NN (NT * TS)   // 65408

typedef __attribute__((ext_vector_type(8))) short short8;
typedef __attribute__((ext_vector_type(4))) short short4v;
typedef __attribute__((ext_vector_type(4))) float floatx4;

__device__ __forceinline__ unsigned short f2b(float f) {
    return __builtin_bit_cast(unsigned short, __float2bfloat16(f));
}
__device__ __forceinline__ float b2f_u(unsigned short u) {
    unsigned v = (unsigned)u << 16;
    return __builtin_bit_cast(float, v);
}
__device__ __forceinline__ float sig_(float x) { return 1.0f / (1.0f + __expf(-x)); }
__device__ __forceinline__ float tanh_(float x) {
    float a = fabsf(x);
    float t = __expf(-2.0f * a);
    float r = (1.0f - t) / (1.0f + t);
    return copysignf(r, x);
}

// ---------------- weight packing ----------------
// Bg [((l*16+kb)*640 + n)*32 + k']  (640-col layout for gemm_level staging)
// BgU[(l*512+col)*128 + k']  col-major U-part: cols 0..383 Ui, 384..511 Uf
// BgX[(l*512+col)*128 + k']  col-major X-part: cols 0..383 Wi, 384..511 Wf
// bp5[(l*5+g)*128+o] biases (g=3,4 both b_f)
__global__ void pack_b(const float* __restrict__ Wiou, const float* __restrict__ biou,
                       const float* __restrict__ Uiou, const float* __restrict__ Wf,
                       const float* __restrict__ bfv, const float* __restrict__ Uf,
                       unsigned short* __restrict__ Bg, unsigned short* __restrict__ BgU,
                       unsigned short* __restrict__ BgX, float* __restrict__ bp5) {
    int tid = blockIdx.x * 256 + threadIdx.x;   // 0..917503
    if (tid < 1280) {
        int l = tid / 640, r = tid % 640, g = r >> 7, o = r & 127;
        bp5[tid] = (g < 3) ? biou[l * 384 + r] : bfv[l * 128 + o];
    }
    if (tid < 655360) {
        int l = tid / 327680;
        int r2 = tid % 327680;
        int n = r2 >> 9, k = r2 & 511;
        int g = n >> 7, o = n & 127;
        float v = 0.f;
        if (g < 3) {
            if (k < 128)       v = Wiou[(l * 384 + g * 128 + o) * 128 + k];
            else if (k < 256)  v = Uiou[(l * 384 + g * 128 + o) * 128 + (k - 128)];
        } else if (g == 3) {
            if (k < 128)                  v = Wf[(l * 128 + o) * 128 + k];
            else if (k >= 256 && k < 384) v = Uf[(l * 128 + o) * 128 + (k - 256)];
        } else {
            if (k < 128)       v = Wf[(l * 128 + o) * 128 + k];
            else if (k >= 384) v = Uf[(l * 128 + o) * 128 + (k - 384)];
        }
        Bg[((size_t)(l * 16 + (k >> 5)) * 640 + n) * 32 + (k & 31)] = f2b(v);
    } else if (tid < 786432) {
        int e2 = tid - 655360;                 // U-part, < 131072
        int l = e2 >> 16, r = e2 & 65535, col = r >> 7, kp = r & 127;
        float v = (col < 384) ? Uiou[(l * 384 + col) * 128 + kp]
                              : Uf[(l * 128 + (col - 384)) * 128 + kp];
        BgU[((size_t)(l * 512 + col)) * 128 + kp] = f2b(v);
    } else {
        int e2 = tid - 786432;                 // X-part, < 131072
        int l = e2 >> 16, r = e2 & 65535, col = r >> 7, kp = r & 127;
        float v = (col < 384) ? Wiou[(l * 384 + col) * 128 + kp]
                              : Wf[(l * 128 + (col - 384)) * 128 + kp];
        BgX[((size_t)(l * 512 + col)) * 128 + kp] = f2b(v);
    }
}

// ---------------- MFMA level GEMM (d=8..5) ----------------
// Block: 64 nodes x NCOLS. 512 threads = 8 waves (2 M-groups x 4 N-groups).
// oheap: output heap base (natural = (1<<d)-1; layer-1 d=5 redirected to 255).
template <int NKB, int NCOLS, bool LEAF>
__global__ __launch_bounds__(512) void gemm_level(
        const float* __restrict__ feat, const unsigned short* __restrict__ Bg,
        const float* __restrict__ bp5, unsigned short* __restrict__ h,
        unsigned short* __restrict__ c, int l, int d, int oheap) {
    constexpr int NI = NCOLS / 64;
    constexpr int BS_BYTES = NCOLS * 40 * 2;
    constexpr int LG_BYTES = 32 * 656 * 2;
    __shared__ char smem[5120 + (BS_BYTES > LG_BYTES ? BS_BYTES : LG_BYTES)];
    unsigned short* As = (unsigned short*)smem;
    unsigned short* Bs = (unsigned short*)(smem + 5120);
    unsigned short* Lg = (unsigned short*)(smem + 5120);

    const int tid = threadIdx.x;
    const int lane = tid & 63, wave = tid >> 6;
    const int wm = wave & 1, wn = wave >> 1;
    const int quad = lane >> 4, l15 = lane & 15;

    const int s = tid & 7, nl_st = tid >> 3;
    const int j_st = blockIdx.x * 64 + nl_st;
    int node_st, ch0_st = 0;
    if (LEAF) {
        node_st = (j_st >> 8) * TS + 255 + (j_st & 255);
    } else {
        int tree = j_st >> d, idx = j_st & ((1 << d) - 1);
        int heap = (1 << d) - 1 + idx;
        node_st = tree * TS + heap;
        ch0_st = tree * TS + 2 * heap + 1;
    }

    floatx4 acc[2][NI];
#pragma unroll
    for (int mi = 0; mi < 2; mi++)
#pragma unroll
        for (int ni = 0; ni < NI; ni++)
            acc[mi][ni] = (floatx4){0.f, 0.f, 0.f, 0.f};

    for (int kb = 0; kb < NKB; kb++) {
        __syncthreads();
        const unsigned short* Bsrc = Bg + ((size_t)(l * 16 + kb) * 640) * 32;
#pragma unroll
        for (int i = 0; i < NCOLS / 128; i++) {
            int flat = i * 512 + tid;
            int n = flat >> 2, chk = flat & 3;
            *(int4*)(Bs + n * 40 + chk * 8) = *(const int4*)(Bsrc + (size_t)n * 32 + chk * 8);
        }
        if (LEAF || kb < 4) {
            float4 xv = *(const float4*)(feat + (size_t)node_st * 128 + kb * 32 + s * 4);
            short4v r;
            r[0] = (short)f2b(xv.x); r[1] = (short)f2b(xv.y);
            r[2] = (short)f2b(xv.z); r[3] = (short)f2b(xv.w);
            *(short4v*)(As + nl_st * 40 + s * 4) = r;
        } else if (kb < 8) {
            int k0 = (kb - 4) * 32 + s * 4;
            short4v a = *(const short4v*)(h + (size_t)ch0_st * 128 + k0);
            short4v b = *(const short4v*)(h + (size_t)(ch0_st + 1) * 128 + k0);
            short4v r;
#pragma unroll
            for (int e = 0; e < 4; e++)
                r[e] = (short)f2b(b2f_u((unsigned short)a[e]) + b2f_u((unsigned short)b[e]));
            *(short4v*)(As + nl_st * 40 + s * 4) = r;
        } else if (kb < 12) {
            int k0 = (kb - 8) * 32 + s * 4;
            *(short4v*)(As + nl_st * 40 + s * 4) =
                *(const short4v*)(h + (size_t)ch0_st * 128 + k0);
        } else {
            int k0 = (kb - 12) * 32 + s * 4;
            *(short4v*)(As + nl_st * 40 + s * 4) =
                *(const short4v*)(h + (size_t)(ch0_st + 1) * 128 + k0);
        }
        __syncthreads();
        short8 a0 = *(const short8*)(As + (wm * 32 + l15) * 40 + quad * 8);
        short8 a1 = *(const short8*)(As + (wm * 32 + 16 + l15) * 40 + quad * 8);
#pragma unroll
        for (int ni = 0; ni < NI; ni++) {
            short8 b = *(const short8*)(Bs + (wn * (NCOLS / 4) + ni * 16 + l15) * 40 + quad * 8);
            acc[0][ni] = __builtin_amdgcn_mfma_f32_16x16x32_bf16(a0, b, acc[0][ni], 0, 0, 0);
            acc[1][ni] = __builtin_amdgcn_mfma_f32_16x16x32_bf16(a1, b, acc[1][ni], 0, 0, 0);
        }
    }

    const int nl_ep = tid >> 4;
    const int t0 = (tid & 15) * 8;
    for (int half = 0; half < 2; half++) {
        __syncthreads();
        if (wm == half) {
#pragma unroll
            for (int mi = 0; mi < 2; mi++)
#pragma unroll
                for (int ni = 0; ni < NI; ni++)
#pragma unroll
                    for (int r = 0; r < 4; r++) {
                        int row = mi * 16 + quad * 4 + r;
                        int col = wn * (NCOLS / 4) + ni * 16 + l15;
                        Lg[row * 656 + col] = f2b(acc[mi][ni][r]);
                    }
        }
        __syncthreads();
        int j = blockIdx.x * 64 + half * 32 + nl_ep;
        int node, ch0 = 0;
        if (LEAF) {
            node = (j >> 8) * TS + 255 + (j & 255);
        } else {
            int tree = j >> d, idx = j & ((1 << d) - 1);
            int heap = (1 << d) - 1 + idx;
            node = tree * TS + oheap + idx;     // output base (may be redirected)
            ch0 = tree * TS + 2 * heap + 1;
        }
        const unsigned short* Lr = Lg + nl_ep * 656 + t0;
        short8 gI = *(const short8*)(Lr);
        short8 gO = *(const short8*)(Lr + 128);
        short8 gU = *(const short8*)(Lr + 256);
        const float* bb = bp5 + (size_t)l * 640 + t0;
        short8 hr, cr;
        if (LEAF) {
#pragma unroll
            for (int e = 0; e < 8; e++) {
                float iv = sig_(b2f_u((unsigned short)gI[e]) + bb[e]);
                float ov = sig_(b2f_u((unsigned short)gO[e]) + bb[128 + e]);
                float uv = tanh_(b2f_u((unsigned short)gU[e]) + bb[256 + e]);
                float cn = iv * uv;
                float hn = ov * tanh_(cn);
                hr[e] = (short)f2b(hn);
                cr[e] = (short)f2b(cn);
            }
        } else {
            short8 gF0 = *(const short8*)(Lr + 384);
            short8 gF1 = *(const short8*)(Lr + 512);
            short8 c0 = *(const short8*)(c + (size_t)ch0 * 128 + t0);
            short8 c1 = *(const short8*)(c + (size_t)(ch0 + 1) * 128 + t0);
#pragma unroll
            for (int e = 0; e < 8; e++) {
                float iv = sig_(b2f_u((unsigned short)gI[e]) + bb[e]);
                float ov = sig_(b2f_u((unsigned short)gO[e]) + bb[128 + e]);
                float uv = tanh_(b2f_u((unsigned short)gU[e]) + bb[256 + e]);
                float f0 = sig_(b2f_u((unsigned short)gF0[e]) + bb[384 + e]);
                float f1 = sig_(b2f_u((unsigned short)gF1[e]) + bb[512 + e]);
                float cn = iv * uv + f0 * b2f_u((unsigned short)c0[e])
                                   + f1 * b2f_u((unsigned short)c1[e]);
                float hn = ov * tanh_(cn);
                hr[e] = (short)f2b(hn);
                cr[e] = (short)f2b(cn);
            }
        }
        *(short8*)(h + (size_t)node * 128 + t0) = hr;
        *(short8*)(c + (size_t)node * 128 + t0) = cr;
    }
}

// ---------------- tail: d=4..0 + root out, fully register-resident B ----------------
// 256 blocks = (layer, tree), 512 threads = 8 waves x 80 cols.
// X-part and U-part B-frags (40 short8/wave) preloaded to VGPRs; f0/f1 share
// Wf/Uf (col-128 alias). x rows + tail h/c live in LDS. 2 barriers per level.
// Layer 0 stages d=5 h/c from natural heaps 31..62; layer 1 from redirected 255..286.
__global__ __launch_bounds__(512) void tail_mfma(
        const float* __restrict__ feat, const unsigned short* __restrict__ BgU,
        const unsigned short* __restrict__ BgX, const float* __restrict__ bp5,
        const unsigned short* __restrict__ h, const unsigned short* __restrict__ c,
        float* __restrict__ out) {
    __shared__ unsigned short xb[31 * 136];
    __shared__ unsigned short hcH[63 * 136];
    __shared__ unsigned short hcC[63 * 136];
    __shared__ unsigned short Lg[16 * 660];

    const int tid = threadIdx.x;
    const int l = blockIdx.x >> 7, tree = blockIdx.x & 127;
    const int lane = tid & 63, w = tid >> 6;
    const int quad = lane >> 4, l15 = lane & 15;
    const unsigned short* BU = BgU + (size_t)l * 512 * 128;
    const unsigned short* BX = BgX + (size_t)l * 512 * 128;
    const float* bb = bp5 + (size_t)l * 640;

    // preload B fragments into registers (reused for all 5 levels)
    short8 bfU[5][4], bfX[5][4];
#pragma unroll
    for (int ni = 0; ni < 5; ni++) {
        int gc0 = w * 80 + ni * 16;
        int col = (gc0 < 512) ? gc0 : gc0 - 128;   // f1 cols alias Uf/Wf at col-128
#pragma unroll
        for (int kbl = 0; kbl < 4; kbl++) {
            bfU[ni][kbl] = *(const short8*)(BU + (size_t)(col + l15) * 128 + kbl * 32 + quad * 8);
            bfX[ni][kbl] = *(const short8*)(BX + (size_t)(col + l15) * 128 + kbl * 32 + quad * 8);
        }
    }
    // stage x (heaps 0..30) and d=5 h/c into cache rows 31..62
    {
        int row = tid >> 4, c8 = (tid & 15) * 8;
        if (row < 31) {
            const float* src = feat + ((size_t)tree * TS + row) * 128 + c8;
            short8 r;
#pragma unroll
            for (int e = 0; e < 8; e++) r[e] = (short)f2b(src[e]);
            *(short8*)(xb + row * 136 + c8) = r;
        }
        int hb = (l == 0) ? 31 : 255;          // layer-1 d=5 was redirected
        *(short8*)(hcH + (31 + row) * 136 + c8) =
            *(const short8*)(h + ((size_t)tree * TS + hb + row) * 128 + c8);
        *(short8*)(hcC + (31 + row) * 136 + c8) =
            *(const short8*)(c + ((size_t)tree * TS + hb + row) * 128 + c8);
    }
    __syncthreads();

    for (int dd = 4; dd >= 0; dd--) {
        const int nd = 1 << dd;
        const int rowA = (l15 < nd) ? l15 : nd - 1;   // clamp: extra rows unused
        const int heap = nd - 1 + rowA;
        floatx4 acc[5];
#pragma unroll
        for (int ni = 0; ni < 5; ni++) acc[ni] = (floatx4){0.f, 0.f, 0.f, 0.f};
#pragma unroll
        for (int kbl = 0; kbl < 4; kbl++) {
            int ko = kbl * 32 + quad * 8;
            short8 ax = *(const short8*)(xb + heap * 136 + ko);
            short8 h0 = *(const short8*)(hcH + (2 * heap + 1) * 136 + ko);
            short8 h1 = *(const short8*)(hcH + (2 * heap + 2) * 136 + ko);
            short8 hs;
#pragma unroll
            for (int e = 0; e < 8; e++)
                hs[e] = (short)f2b(b2f_u((unsigned short)h0[e]) +
                                   b2f_u((unsigned short)h1[e]));
#pragma unroll
            for (int ni = 0; ni < 5; ni++) {
                int gc0 = w * 80 + ni * 16;
                short8 a = (gc0 < 384) ? hs : ((gc0 < 512) ? h0 : h1);
                acc[ni] = __builtin_amdgcn_mfma_f32_16x16x32_bf16(ax, bfX[ni][kbl],
                                                                  acc[ni], 0, 0, 0);
                acc[ni] = __builtin_amdgcn_mfma_f32_16x16x32_bf16(a, bfU[ni][kbl],
                                                                  acc[ni], 0, 0, 0);
            }
        }
#pragma unroll
        for (int ni = 0; ni < 5; ni++)
#pragma unroll
            for (int r = 0; r < 4; r++)
                Lg[(quad * 4 + r) * 660 + w * 80 + ni * 16 + l15] = f2b(acc[ni][r]);
        __syncthreads();
        for (int idx = tid; idx < nd * 128; idx += 512) {
            int node = idx >> 7, t = idx & 127;
            int hp = nd - 1 + node;
            const unsigned short* Lr = Lg + node * 660;
            float iv = sig_(b2f_u(Lr[t]) + bb[t]);
            float ov = sig_(b2f_u(Lr[128 + t]) + bb[128 + t]);
            float uv = tanh_(b2f_u(Lr[256 + t]) + bb[256 + t]);
            float f0 = sig_(b2f_u(Lr[384 + t]) + bb[384 + t]);
            float f1 = sig_(b2f_u(Lr[512 + t]) + bb[512 + t]);
            float c0v = b2f_u(hcC[(2 * hp + 1) * 136 + t]);
            float c1v = b2f_u(hcC[(2 * hp + 2) * 136 + t]);
            float cn = iv * uv + f0 * c0v + f1 * c1v;
            float hn = ov * tanh_(cn);
            hcH[hp * 136 + t] = f2b(hn);
            hcC[hp * 136 + t] = f2b(cn);
            if (dd == 0) {
                out[((size_t)l * 128 + tree) * 128 + t] = hn;
                out[32768 + ((size_t)l * 128 + tree) * 128 + t] = cn;
            }
        }
        __syncthreads();
    }
}

extern "C" void kernel_launch(void* const* d_in, const int* in_sizes, int n_in,
                              void* d_out, int out_size, void* d_ws, size_t ws_size,
                              hipStream_t stream) {
    const float* feat = (const float*)d_in[0];
    const float* Wiou = (const float*)d_in[1];
    const float* biou = (const float*)d_in[2];
    const float* Uiou = (const float*)d_in[3];
    const float* Wf   = (const float*)d_in[4];
    const float* bfv  = (const float*)d_in[5];
    const float* Uf   = (const float*)d_in[6];
    float* out = (float*)d_out;

    // ws (bf16 shorts unless noted): h[NN*128] c[NN*128] Bg[655360]
    //   BgU[131072] BgX[131072] bp5(f32)[1280]   total ~35.3 MB
    unsigned short* h   = (unsigned short*)d_ws;
    unsigned short* c   = h + (size_t)NN * 128;
    unsigned short* Bg  = c + (size_t)NN * 128;
    unsigned short* BgU = Bg + (size_t)655360;
    unsigned short* BgX = BgU + (size_t)131072;
    float* bp5 = (float*)(BgX + (size_t)131072);

    pack_b<<<3584, 256, 0, stream>>>(Wiou, biou, Uiou, Wf, bfv, Uf, Bg, BgU, BgX, bp5);

    for (int l = 0; l < 2; l++) {
        gemm_level<4, 384, true><<<512, 512, 0, stream>>>(feat, Bg, bp5, h, c, l, 0, 0);
        gemm_level<16, 640, false><<<256, 512, 0, stream>>>(feat, Bg, bp5, h, c, l, 7, 127);
        gemm_level<16, 640, false><<<128, 512, 0, stream>>>(feat, Bg, bp5, h, c, l, 6, 63);
        // layer 1's d=5 output redirected to dead heaps 255..286 so layer 0's
        // natural heaps 31..62 survive for the merged tail
        gemm_level<16, 640, false><<<64, 512, 0, stream>>>(feat, Bg, bp5, h, c, l, 5,
                                                           (l == 0) ? 31 : 255);
    }
    tail_mfma<<<256, 512, 0, stream>>>(feat, BgU, BgX, bp5, h, c, out);
}

// Round 10
// 269.370 us; speedup vs baseline: 1.7764x; 1.2129x over previous
//
#include <hip/hip_runtime.h>
#include <hip/hip_bf16.h>

// TreeLSTM on MI355X — MFMA formulation, round 10.
// 128 trees, heap layout, TREE_SIZE=511, depth 9; children of heap h: 2h+1, 2h+2.
// Gates: A-row = [x | h0+h1 | h0 | h1] (K=512) @ B (512x640), col blocks [i|o|u|f0|f1].
// BOTH LAYERS MERGED into each dispatch (layers are independent; separate h/c
// state per layer — ws is ~268 MB per R9's poison-fill evidence, 69 MB used).
// Chain: pack -> leaf(d8) -> d7 -> d6 -> d5 -> tail(d4..0 + root out). 6 dispatches.
// Tail: per-(layer,tree) block; B x-part AND U-part register-resident
//   (f0/f1 share Wf/Uf via col-128 alias), x + h/c in LDS, 2 barriers/level.

#define TS 511
#define NT 128
#define NN (NT * TS)   // 65408

typedef __attribute__((ext_vector_type(8))) short short8;
typedef __attribute__((ext_vector_type(4))) short short4v;
typedef __attribute__((ext_vector_type(4))) float floatx4;

__device__ __forceinline__ unsigned short f2b(float f) {
    return __builtin_bit_cast(unsigned short, __float2bfloat16(f));
}
__device__ __forceinline__ float b2f_u(unsigned short u) {
    unsigned v = (unsigned)u << 16;
    return __builtin_bit_cast(float, v);
}
__device__ __forceinline__ float sig_(float x) { return 1.0f / (1.0f + __expf(-x)); }
__device__ __forceinline__ float tanh_(float x) {
    float a = fabsf(x);
    float t = __expf(-2.0f * a);
    float r = (1.0f - t) / (1.0f + t);
    return copysignf(r, x);
}

// ---------------- weight packing ----------------
// Bg [((l*16+kb)*640 + n)*32 + k']  (640-col layout for gemm_level staging)
// BgU[(l*512+col)*128 + k']  col-major U-part: cols 0..383 Ui, 384..511 Uf
// BgX[(l*512+col)*128 + k']  col-major X-part: cols 0..383 Wi, 384..511 Wf
// bp5[(l*5+g)*128+o] biases (g=3,4 both b_f)
__global__ void pack_b(const float* __restrict__ Wiou, const float* __restrict__ biou,
                       const float* __restrict__ Uiou, const float* __restrict__ Wf,
                       const float* __restrict__ bfv, const float* __restrict__ Uf,
                       unsigned short* __restrict__ Bg, unsigned short* __restrict__ BgU,
                       unsigned short* __restrict__ BgX, float* __restrict__ bp5) {
    int tid = blockIdx.x * 256 + threadIdx.x;   // 0..917503
    if (tid < 1280) {
        int l = tid / 640, r = tid % 640, g = r >> 7, o = r & 127;
        bp5[tid] = (g < 3) ? biou[l * 384 + r] : bfv[l * 128 + o];
    }
    if (tid < 655360) {
        int l = tid / 327680;
        int r2 = tid % 327680;
        int n = r2 >> 9, k = r2 & 511;
        int g = n >> 7, o = n & 127;
        float v = 0.f;
        if (g < 3) {
            if (k < 128)       v = Wiou[(l * 384 + g * 128 + o) * 128 + k];
            else if (k < 256)  v = Uiou[(l * 384 + g * 128 + o) * 128 + (k - 128)];
        } else if (g == 3) {
            if (k < 128)                  v = Wf[(l * 128 + o) * 128 + k];
            else if (k >= 256 && k < 384) v = Uf[(l * 128 + o) * 128 + (k - 256)];
        } else {
            if (k < 128)       v = Wf[(l * 128 + o) * 128 + k];
            else if (k >= 384) v = Uf[(l * 128 + o) * 128 + (k - 384)];
        }
        Bg[((size_t)(l * 16 + (k >> 5)) * 640 + n) * 32 + (k & 31)] = f2b(v);
    } else if (tid < 786432) {
        int e2 = tid - 655360;                 // U-part, < 131072
        int l = e2 >> 16, r = e2 & 65535, col = r >> 7, kp = r & 127;
        float v = (col < 384) ? Uiou[(l * 384 + col) * 128 + kp]
                              : Uf[(l * 128 + (col - 384)) * 128 + kp];
        BgU[((size_t)(l * 512 + col)) * 128 + kp] = f2b(v);
    } else {
        int e2 = tid - 786432;                 // X-part, < 131072
        int l = e2 >> 16, r = e2 & 65535, col = r >> 7, kp = r & 127;
        float v = (col < 384) ? Wiou[(l * 384 + col) * 128 + kp]
                              : Wf[(l * 128 + (col - 384)) * 128 + kp];
        BgX[((size_t)(l * 512 + col)) * 128 + kp] = f2b(v);
    }
}

// ---------------- MFMA level GEMM (d=8..5), both layers in one dispatch ----------
// Block: 64 nodes x NCOLS. 512 threads = 8 waves (2 M-groups x 4 N-groups).
// l = blockIdx.x >> lshift ; per-layer h/c state at hb/cb + l*NN*128.
template <int NKB, int NCOLS, bool LEAF>
__global__ __launch_bounds__(512) void gemm_level(
        const float* __restrict__ feat, const unsigned short* __restrict__ Bg,
        const float* __restrict__ bp5, unsigned short* __restrict__ hb,
        unsigned short* __restrict__ cb, int d, int lshift) {
    constexpr int NI = NCOLS / 64;
    constexpr int BS_BYTES = NCOLS * 40 * 2;
    constexpr int LG_BYTES = 32 * 656 * 2;
    __shared__ char smem[5120 + (BS_BYTES > LG_BYTES ? BS_BYTES : LG_BYTES)];
    unsigned short* As = (unsigned short*)smem;
    unsigned short* Bs = (unsigned short*)(smem + 5120);
    unsigned short* Lg = (unsigned short*)(smem + 5120);

    const int tid = threadIdx.x;
    const int l = blockIdx.x >> lshift;
    const int bx = blockIdx.x & ((1 << lshift) - 1);
    unsigned short* h = hb + (size_t)l * NN * 128;
    unsigned short* c = cb + (size_t)l * NN * 128;

    const int lane = tid & 63, wave = tid >> 6;
    const int wm = wave & 1, wn = wave >> 1;
    const int quad = lane >> 4, l15 = lane & 15;

    const int s = tid & 7, nl_st = tid >> 3;
    const int j_st = bx * 64 + nl_st;
    int node_st, ch0_st = 0;
    if (LEAF) {
        node_st = (j_st >> 8) * TS + 255 + (j_st & 255);
    } else {
        int tree = j_st >> d, idx = j_st & ((1 << d) - 1);
        int heap = (1 << d) - 1 + idx;
        node_st = tree * TS + heap;
        ch0_st = tree * TS + 2 * heap + 1;
    }

    floatx4 acc[2][NI];
#pragma unroll
    for (int mi = 0; mi < 2; mi++)
#pragma unroll
        for (int ni = 0; ni < NI; ni++)
            acc[mi][ni] = (floatx4){0.f, 0.f, 0.f, 0.f};

    for (int kb = 0; kb < NKB; kb++) {
        __syncthreads();
        const unsigned short* Bsrc = Bg + ((size_t)(l * 16 + kb) * 640) * 32;
#pragma unroll
        for (int i = 0; i < NCOLS / 128; i++) {
            int flat = i * 512 + tid;
            int n = flat >> 2, chk = flat & 3;
            *(int4*)(Bs + n * 40 + chk * 8) = *(const int4*)(Bsrc + (size_t)n * 32 + chk * 8);
        }
        if (LEAF || kb < 4) {
            float4 xv = *(const float4*)(feat + (size_t)node_st * 128 + kb * 32 + s * 4);
            short4v r;
            r[0] = (short)f2b(xv.x); r[1] = (short)f2b(xv.y);
            r[2] = (short)f2b(xv.z); r[3] = (short)f2b(xv.w);
            *(short4v*)(As + nl_st * 40 + s * 4) = r;
        } else if (kb < 8) {
            int k0 = (kb - 4) * 32 + s * 4;
            short4v a = *(const short4v*)(h + (size_t)ch0_st * 128 + k0);
            short4v b = *(const short4v*)(h + (size_t)(ch0_st + 1) * 128 + k0);
            short4v r;
#pragma unroll
            for (int e = 0; e < 4; e++)
                r[e] = (short)f2b(b2f_u((unsigned short)a[e]) + b2f_u((unsigned short)b[e]));
            *(short4v*)(As + nl_st * 40 + s * 4) = r;
        } else if (kb < 12) {
            int k0 = (kb - 8) * 32 + s * 4;
            *(short4v*)(As + nl_st * 40 + s * 4) =
                *(const short4v*)(h + (size_t)ch0_st * 128 + k0);
        } else {
            int k0 = (kb - 12) * 32 + s * 4;
            *(short4v*)(As + nl_st * 40 + s * 4) =
                *(const short4v*)(h + (size_t)(ch0_st + 1) * 128 + k0);
        }
        __syncthreads();
        short8 a0 = *(const short8*)(As + (wm * 32 + l15) * 40 + quad * 8);
        short8 a1 = *(const short8*)(As + (wm * 32 + 16 + l15) * 40 + quad * 8);
#pragma unroll
        for (int ni = 0; ni < NI; ni++) {
            short8 b = *(const short8*)(Bs + (wn * (NCOLS / 4) + ni * 16 + l15) * 40 + quad * 8);
            acc[0][ni] = __builtin_amdgcn_mfma_f32_16x16x32_bf16(a0, b, acc[0][ni], 0, 0, 0);
            acc[1][ni] = __builtin_amdgcn_mfma_f32_16x16x32_bf16(a1, b, acc[1][ni], 0, 0, 0);
        }
    }

    const int nl_ep = tid >> 4;
    const int t0 = (tid & 15) * 8;
    for (int half = 0; half < 2; half++) {
        __syncthreads();
        if (wm == half) {
#pragma unroll
            for (int mi = 0; mi < 2; mi++)
#pragma unroll
                for (int ni = 0; ni < NI; ni++)
#pragma unroll
                    for (int r = 0; r < 4; r++) {
                        int row = mi * 16 + quad * 4 + r;
                        int col = wn * (NCOLS / 4) + ni * 16 + l15;
                        Lg[row * 656 + col] = f2b(acc[mi][ni][r]);
                    }
        }
        __syncthreads();
        int j = bx * 64 + half * 32 + nl_ep;
        int node, ch0 = 0;
        if (LEAF) {
            node = (j >> 8) * TS + 255 + (j & 255);
        } else {
            int tree = j >> d, idx = j & ((1 << d) - 1);
            int heap = (1 << d) - 1 + idx;
            node = tree * TS + heap;
            ch0 = tree * TS + 2 * heap + 1;
        }
        const unsigned short* Lr = Lg + nl_ep * 656 + t0;
        short8 gI = *(const short8*)(Lr);
        short8 gO = *(const short8*)(Lr + 128);
        short8 gU = *(const short8*)(Lr + 256);
        const float* bb = bp5 + (size_t)l * 640 + t0;
        short8 hr, cr;
        if (LEAF) {
#pragma unroll
            for (int e = 0; e < 8; e++) {
                float iv = sig_(b2f_u((unsigned short)gI[e]) + bb[e]);
                float ov = sig_(b2f_u((unsigned short)gO[e]) + bb[128 + e]);
                float uv = tanh_(b2f_u((unsigned short)gU[e]) + bb[256 + e]);
                float cn = iv * uv;
                float hn = ov * tanh_(cn);
                hr[e] = (short)f2b(hn);
                cr[e] = (short)f2b(cn);
            }
        } else {
            short8 gF0 = *(const short8*)(Lr + 384);
            short8 gF1 = *(const short8*)(Lr + 512);
            short8 c0 = *(const short8*)(c + (size_t)ch0 * 128 + t0);
            short8 c1 = *(const short8*)(c + (size_t)(ch0 + 1) * 128 + t0);
#pragma unroll
            for (int e = 0; e < 8; e++) {
                float iv = sig_(b2f_u((unsigned short)gI[e]) + bb[e]);
                float ov = sig_(b2f_u((unsigned short)gO[e]) + bb[128 + e]);
                float uv = tanh_(b2f_u((unsigned short)gU[e]) + bb[256 + e]);
                float f0 = sig_(b2f_u((unsigned short)gF0[e]) + bb[384 + e]);
                float f1 = sig_(b2f_u((unsigned short)gF1[e]) + bb[512 + e]);
                float cn = iv * uv + f0 * b2f_u((unsigned short)c0[e])
                                   + f1 * b2f_u((unsigned short)c1[e]);
                float hn = ov * tanh_(cn);
                hr[e] = (short)f2b(hn);
                cr[e] = (short)f2b(cn);
            }
        }
        *(short8*)(h + (size_t)node * 128 + t0) = hr;
        *(short8*)(c + (size_t)node * 128 + t0) = cr;
    }
}

// ---------------- tail: d=4..0 + root out, fully register-resident B ----------------
// 256 blocks = (layer, tree), 512 threads = 8 waves x 80 cols.
// X-part and U-part B-frags (40 short8/wave) preloaded to VGPRs; f0/f1 share
// Wf/Uf (col-128 alias). x rows + tail h/c live in LDS. 2 barriers per level.
__global__ __launch_bounds__(512) void tail_mfma(
        const float* __restrict__ feat, const unsigned short* __restrict__ BgU,
        const unsigned short* __restrict__ BgX, const float* __restrict__ bp5,
        const unsigned short* __restrict__ hb, const unsigned short* __restrict__ cb,
        float* __restrict__ out) {
    __shared__ unsigned short xb[31 * 136];
    __shared__ unsigned short hcH[63 * 136];
    __shared__ unsigned short hcC[63 * 136];
    __shared__ unsigned short Lg[16 * 660];

    const int tid = threadIdx.x;
    const int l = blockIdx.x >> 7, tree = blockIdx.x & 127;
    const int lane = tid & 63, w = tid >> 6;
    const int quad = lane >> 4, l15 = lane & 15;
    const unsigned short* BU = BgU + (size_t)l * 512 * 128;
    const unsigned short* BX = BgX + (size_t)l * 512 * 128;
    const unsigned short* h = hb + (size_t)l * NN * 128;
    const unsigned short* c = cb + (size_t)l * NN * 128;
    const float* bb = bp5 + (size_t)l * 640;

    // preload B fragments into registers (reused for all 5 levels)
    short8 bfU[5][4], bfX[5][4];
#pragma unroll
    for (int ni = 0; ni < 5; ni++) {
        int gc0 = w * 80 + ni * 16;
        int col = (gc0 < 512) ? gc0 : gc0 - 128;   // f1 cols alias Uf/Wf at col-128
#pragma unroll
        for (int kbl = 0; kbl < 4; kbl++) {
            bfU[ni][kbl] = *(const short8*)(BU + (size_t)(col + l15) * 128 + kbl * 32 + quad * 8);
            bfX[ni][kbl] = *(const short8*)(BX + (size_t)(col + l15) * 128 + kbl * 32 + quad * 8);
        }
    }
    // stage x (heaps 0..30) and d=5 h/c (natural heaps 31..62) into LDS
    {
        int row = tid >> 4, c8 = (tid & 15) * 8;
        if (row < 31) {
            const float* src = feat + ((size_t)tree * TS + row) * 128 + c8;
            short8 r;
#pragma unroll
            for (int e = 0; e < 8; e++) r[e] = (short)f2b(src[e]);
            *(short8*)(xb + row * 136 + c8) = r;
        }
        *(short8*)(hcH + (31 + row) * 136 + c8) =
            *(const short8*)(h + ((size_t)tree * TS + 31 + row) * 128 + c8);
        *(short8*)(hcC + (31 + row) * 136 + c8) =
            *(const short8*)(c + ((size_t)tree * TS + 31 + row) * 128 + c8);
    }
    __syncthreads();

    for (int dd = 4; dd >= 0; dd--) {
        const int nd = 1 << dd;
        const int rowA = (l15 < nd) ? l15 : nd - 1;   // clamp: extra rows unused
        const int heap = nd - 1 + rowA;
        floatx4 acc[5];
#pragma unroll
        for (int ni = 0; ni < 5; ni++) acc[ni] = (floatx4){0.f, 0.f, 0.f, 0.f};
#pragma unroll
        for (int kbl = 0; kbl < 4; kbl++) {
            int ko = kbl * 32 + quad * 8;
            short8 ax = *(const short8*)(xb + heap * 136 + ko);
            short8 h0 = *(const short8*)(hcH + (2 * heap + 1) * 136 + ko);
            short8 h1 = *(const short8*)(hcH + (2 * heap + 2) * 136 + ko);
            short8 hs;
#pragma unroll
            for (int e = 0; e < 8; e++)
                hs[e] = (short)f2b(b2f_u((unsigned short)h0[e]) +
                                   b2f_u((unsigned short)h1[e]));
#pragma unroll
            for (int ni = 0; ni < 5; ni++) {
                int gc0 = w * 80 + ni * 16;
                short8 a = (gc0 < 384) ? hs : ((gc0 < 512) ? h0 : h1);
                acc[ni] = __builtin_amdgcn_mfma_f32_16x16x32_bf16(ax, bfX[ni][kbl],
                                                                  acc[ni], 0, 0, 0);
                acc[ni] = __builtin_amdgcn_mfma_f32_16x16x32_bf16(a, bfU[ni][kbl],
                                                                  acc[ni], 0, 0, 0);
            }
        }
#pragma unroll
        for (int ni = 0; ni < 5; ni++)
#pragma unroll
            for (int r = 0; r < 4; r++)
                Lg[(quad * 4 + r) * 660 + w * 80 + ni * 16 + l15] = f2b(acc[ni][r]);
        __syncthreads();
        for (int idx = tid; idx < nd * 128; idx += 512) {
            int node = idx >> 7, t = idx & 127;
            int hp = nd - 1 + node;
            const unsigned short* Lr = Lg + node * 660;
            float iv = sig_(b2f_u(Lr[t]) + bb[t]);
            float ov = sig_(b2f_u(Lr[128 + t]) + bb[128 + t]);
            float uv = tanh_(b2f_u(Lr[256 + t]) + bb[256 + t]);
            float f0 = sig_(b2f_u(Lr[384 + t]) + bb[384 + t]);
            float f1 = sig_(b2f_u(Lr[512 + t]) + bb[512 + t]);
            float c0v = b2f_u(hcC[(2 * hp + 1) * 136 + t]);
            float c1v = b2f_u(hcC[(2 * hp + 2) * 136 + t]);
            float cn = iv * uv + f0 * c0v + f1 * c1v;
            float hn = ov * tanh_(cn);
            hcH[hp * 136 + t] = f2b(hn);
            hcC[hp * 136 + t] = f2b(cn);
            if (dd == 0) {
                out[((size_t)l * 128 + tree) * 128 + t] = hn;
                out[32768 + ((size_t)l * 128 + tree) * 128 + t] = cn;
            }
        }
        __syncthreads();
    }
}

extern "C" void kernel_launch(void* const* d_in, const int* in_sizes, int n_in,
                              void* d_out, int out_size, void* d_ws, size_t ws_size,
                              hipStream_t stream) {
    const float* feat = (const float*)d_in[0];
    const float* Wiou = (const float*)d_in[1];
    const float* biou = (const float*)d_in[2];
    const float* Uiou = (const float*)d_in[3];
    const float* Wf   = (const float*)d_in[4];
    const float* bfv  = (const float*)d_in[5];
    const float* Uf   = (const float*)d_in[6];
    float* out = (float*)d_out;

    // ws (bf16 shorts unless noted): h[2][NN*128] c[2][NN*128] Bg[655360]
    //   BgU[131072] BgX[131072] bp5(f32)[1280]   total ~68.8 MB (ws ~268 MB)
    unsigned short* hb  = (unsigned short*)d_ws;
    unsigned short* cb  = hb + (size_t)2 * NN * 128;
    unsigned short* Bg  = cb + (size_t)2 * NN * 128;
    unsigned short* BgU = Bg + (size_t)655360;
    unsigned short* BgX = BgU + (size_t)131072;
    float* bp5 = (float*)(BgX + (size_t)131072);

    pack_b<<<3584, 256, 0, stream>>>(Wiou, biou, Uiou, Wf, bfv, Uf, Bg, BgU, BgX, bp5);

    // both layers in every dispatch
    gemm_level<4, 384, true><<<1024, 512, 0, stream>>>(feat, Bg, bp5, hb, cb, 0, 9);
    gemm_level<16, 640, false><<<512, 512, 0, stream>>>(feat, Bg, bp5, hb, cb, 7, 8);
    gemm_level<16, 640, false><<<256, 512, 0, stream>>>(feat, Bg, bp5, hb, cb, 6, 7);
    gemm_level<16, 640, false><<<128, 512, 0, stream>>>(feat, Bg, bp5, hb, cb, 5, 6);
    tail_mfma<<<256, 512, 0, stream>>>(feat, BgU, BgX, bp5, hb, cb, out);
}

// Round 11
// 250.263 us; speedup vs baseline: 1.9121x; 1.0763x over previous
//
#include <hip/hip_runtime.h>
#include <hip/hip_bf16.h>

// TreeLSTM on MI355X — MFMA formulation, round 11.
// 128 trees, heap layout, TREE_SIZE=511, depth 9; children of heap h: 2h+1, 2h+2.
// Gates GEMM: A-row = [x | h0 | h1] (K=384; Ui appears in BOTH h-ranges — linearity
//   replaces the hsum row) @ B (384x640), col blocks [i|o|u|f0|f1].
// Gate-aligned tiles: wave wn owns cols g*128 + wn*32 + ch*16, so all 5 gates of an
//   output feature land in one lane -> full-register epilogue (no LDS gate buffer).
// Both layers merged per dispatch; 6 dispatches total. Tail (d4..0) unchanged from R10.

#define TS 511
#define NT 128
#define NN (NT * TS)   // 65408

typedef __attribute__((ext_vector_type(8))) short short8;
typedef __attribute__((ext_vector_type(4))) short short4v;
typedef __attribute__((ext_vector_type(4))) float floatx4;

__device__ __forceinline__ unsigned short f2b(float f) {
    return __builtin_bit_cast(unsigned short, __float2bfloat16(f));
}
__device__ __forceinline__ float b2f_u(unsigned short u) {
    unsigned v = (unsigned)u << 16;
    return __builtin_bit_cast(float, v);
}
__device__ __forceinline__ float sig_(float x) { return 1.0f / (1.0f + __expf(-x)); }
__device__ __forceinline__ float tanh_(float x) {
    float a = fabsf(x);
    float t = __expf(-2.0f * a);
    float r = (1.0f - t) / (1.0f + t);
    return copysignf(r, x);
}

// ---------------- weight packing ----------------
// Bg2[((l*12+kb)*640 + n)*32 + kp]: K=384 layout. kb0-3: x-range (Wi / Wf / Wf).
//   kb4-7: h0-range (Ui / Uf / 0). kb8-11: h1-range (Ui / 0 / Uf).
// BgU[(l*512+col)*128+kp] col-major U (tail): 0..383 Ui, 384..511 Uf.
// BgX[(l*512+col)*128+kp] col-major X (tail): 0..383 Wi, 384..511 Wf.
// bp5[(l*5+g)*128+o] biases (g=3,4 both b_f).
__global__ void pack_b(const float* __restrict__ Wiou, const float* __restrict__ biou,
                       const float* __restrict__ Uiou, const float* __restrict__ Wf,
                       const float* __restrict__ bfv, const float* __restrict__ Uf,
                       unsigned short* __restrict__ Bg, unsigned short* __restrict__ BgU,
                       unsigned short* __restrict__ BgX, float* __restrict__ bp5) {
    int tid = blockIdx.x * 256 + threadIdx.x;   // 0..753663
    if (tid < 1280) {
        int l = tid / 640, r = tid % 640, g = r >> 7, o = r & 127;
        bp5[tid] = (g < 3) ? biou[l * 384 + r] : bfv[l * 128 + o];
    }
    if (tid < 491520) {
        int l = tid / 245760;
        int r = tid % 245760;
        int kb = r / 20480;
        int r2 = r % 20480;
        int n = r2 >> 5, kp = r2 & 31;
        int g = n >> 7, o = n & 127;
        float v = 0.f;
        if (kb < 4) {
            int k = kb * 32 + kp;
            v = (g < 3) ? Wiou[(l * 384 + g * 128 + o) * 128 + k]
                        : Wf[(l * 128 + o) * 128 + k];
        } else if (kb < 8) {
            int k = (kb - 4) * 32 + kp;
            if (g < 3)       v = Uiou[(l * 384 + g * 128 + o) * 128 + k];
            else if (g == 3) v = Uf[(l * 128 + o) * 128 + k];
        } else {
            int k = (kb - 8) * 32 + kp;
            if (g < 3)       v = Uiou[(l * 384 + g * 128 + o) * 128 + k];
            else if (g == 4) v = Uf[(l * 128 + o) * 128 + k];
        }
        Bg[tid] = f2b(v);
    } else if (tid < 622592) {
        int e2 = tid - 491520;                 // U-part, < 131072
        int l = e2 >> 16, r = e2 & 65535, col = r >> 7, kp = r & 127;
        float v = (col < 384) ? Uiou[(l * 384 + col) * 128 + kp]
                              : Uf[(l * 128 + (col - 384)) * 128 + kp];
        BgU[((size_t)(l * 512 + col)) * 128 + kp] = f2b(v);
    } else {
        int e2 = tid - 622592;                 // X-part, < 131072
        int l = e2 >> 16, r = e2 & 65535, col = r >> 7, kp = r & 127;
        float v = (col < 384) ? Wiou[(l * 384 + col) * 128 + kp]
                              : Wf[(l * 128 + (col - 384)) * 128 + kp];
        BgX[((size_t)(l * 512 + col)) * 128 + kp] = f2b(v);
    }
}

// ---------------- MFMA level GEMM (d=8..5), register epilogue ----------------
// Block: 64 nodes x NCOLS. 512 threads = 8 waves (2 M-groups x 4 N-groups).
// Wave wn owns tiles ni = g*2+ch at col g*128 + wn*32 + ch*16 (gate-aligned).
template <int NKB, int NCOLS, bool LEAF>
__global__ __launch_bounds__(512) void gemm_level(
        const float* __restrict__ feat, const unsigned short* __restrict__ Bg,
        const float* __restrict__ bp5, unsigned short* __restrict__ hb,
        unsigned short* __restrict__ cb, int d, int lshift) {
    constexpr int NI = NCOLS / 64;            // 6 (leaf) or 10
    __shared__ unsigned short As[64 * 40];
    __shared__ unsigned short Bs[NCOLS * 40];

    const int tid = threadIdx.x;
    const int l = blockIdx.x >> lshift;
    const int bx = blockIdx.x & ((1 << lshift) - 1);
    unsigned short* h = hb + (size_t)l * NN * 128;
    unsigned short* c = cb + (size_t)l * NN * 128;

    const int lane = tid & 63, wave = tid >> 6;
    const int wm = wave & 1, wn = wave >> 1;
    const int quad = lane >> 4, l15 = lane & 15;

    const int s = tid & 7, nl_st = tid >> 3;
    const int j_st = bx * 64 + nl_st;
    int node_st, ch0_st = 0;
    if (LEAF) {
        node_st = (j_st >> 8) * TS + 255 + (j_st & 255);
    } else {
        int tree = j_st >> d, idx = j_st & ((1 << d) - 1);
        int heap = (1 << d) - 1 + idx;
        node_st = tree * TS + heap;
        ch0_st = tree * TS + 2 * heap + 1;
    }

    floatx4 acc[2][NI];
#pragma unroll
    for (int mi = 0; mi < 2; mi++)
#pragma unroll
        for (int ni = 0; ni < NI; ni++)
            acc[mi][ni] = (floatx4){0.f, 0.f, 0.f, 0.f};

    for (int kb = 0; kb < NKB; kb++) {
        __syncthreads();
        const unsigned short* Bsrc = Bg + ((size_t)(l * 12 + kb) * 640) * 32;
#pragma unroll
        for (int i = 0; i < NCOLS / 128; i++) {
            int flat = i * 512 + tid;
            int n = flat >> 2, chk = flat & 3;
            *(int4*)(Bs + n * 40 + chk * 8) = *(const int4*)(Bsrc + (size_t)n * 32 + chk * 8);
        }
        if (LEAF || kb < 4) {
            float4 xv = *(const float4*)(feat + (size_t)node_st * 128 + kb * 32 + s * 4);
            short4v r;
            r[0] = (short)f2b(xv.x); r[1] = (short)f2b(xv.y);
            r[2] = (short)f2b(xv.z); r[3] = (short)f2b(xv.w);
            *(short4v*)(As + nl_st * 40 + s * 4) = r;
        } else if (kb < 8) {
            int k0 = (kb - 4) * 32 + s * 4;   // h0 raw
            *(short4v*)(As + nl_st * 40 + s * 4) =
                *(const short4v*)(h + (size_t)ch0_st * 128 + k0);
        } else {
            int k0 = (kb - 8) * 32 + s * 4;   // h1 raw
            *(short4v*)(As + nl_st * 40 + s * 4) =
                *(const short4v*)(h + (size_t)(ch0_st + 1) * 128 + k0);
        }
        __syncthreads();
        short8 a0 = *(const short8*)(As + (wm * 32 + l15) * 40 + quad * 8);
        short8 a1 = *(const short8*)(As + (wm * 32 + 16 + l15) * 40 + quad * 8);
#pragma unroll
        for (int ni = 0; ni < NI; ni++) {
            const int g = ni >> 1;
            if (!LEAF) {   // skip structural-zero B tiles (wave-uniform)
                if (g == 3 && kb >= 8) continue;
                if (g == 4 && kb >= 4 && kb < 8) continue;
            }
            int col = g * 128 + wn * 32 + (ni & 1) * 16;
            short8 b = *(const short8*)(Bs + (col + l15) * 40 + quad * 8);
            acc[0][ni] = __builtin_amdgcn_mfma_f32_16x16x32_bf16(a0, b, acc[0][ni], 0, 0, 0);
            acc[1][ni] = __builtin_amdgcn_mfma_f32_16x16x32_bf16(a1, b, acc[1][ni], 0, 0, 0);
        }
    }

    // -------- register epilogue: lane owns all gates of features o=wn*32+ch*16+l15
    float bbv[NI];
#pragma unroll
    for (int ni = 0; ni < NI; ni++)
        bbv[ni] = bp5[l * 640 + (ni >> 1) * 128 + wn * 32 + (ni & 1) * 16 + l15];

#pragma unroll
    for (int mi = 0; mi < 2; mi++) {
        int nodes[4];
        unsigned short c0v[4][2], c1v[4][2];
#pragma unroll
        for (int r = 0; r < 4; r++) {
            int row = wm * 32 + mi * 16 + quad * 4 + r;
            int j = bx * 64 + row;
            if (LEAF) {
                nodes[r] = (j >> 8) * TS + 255 + (j & 255);
            } else {
                int tree = j >> d, idx = j & ((1 << d) - 1);
                int heap = (1 << d) - 1 + idx;
                nodes[r] = tree * TS + heap;
                int ch0 = tree * TS + 2 * heap + 1;
#pragma unroll
                for (int ch = 0; ch < 2; ch++) {
                    int o = wn * 32 + ch * 16 + l15;
                    c0v[r][ch] = c[(size_t)ch0 * 128 + o];
                    c1v[r][ch] = c[(size_t)(ch0 + 1) * 128 + o];
                }
            }
        }
#pragma unroll
        for (int r = 0; r < 4; r++) {
#pragma unroll
            for (int ch = 0; ch < 2; ch++) {
                int o = wn * 32 + ch * 16 + l15;
                float iv = sig_(acc[mi][0 + ch][r] + bbv[0 + ch]);
                float ov = sig_(acc[mi][2 + ch][r] + bbv[2 + ch]);
                float uv = tanh_(acc[mi][4 + ch][r] + bbv[4 + ch]);
                float cn;
                if (LEAF) {
                    cn = iv * uv;
                } else {
                    float f0 = sig_(acc[mi][6 + ch][r] + bbv[6 + ch]);
                    float f1 = sig_(acc[mi][8 + ch][r] + bbv[8 + ch]);
                    cn = iv * uv + f0 * b2f_u(c0v[r][ch]) + f1 * b2f_u(c1v[r][ch]);
                }
                float hn = ov * tanh_(cn);
                h[(size_t)nodes[r] * 128 + o] = f2b(hn);
                c[(size_t)nodes[r] * 128 + o] = f2b(cn);
            }
        }
    }
}

// ---------------- tail: d=4..0 + root out, fully register-resident B ----------------
// 256 blocks = (layer, tree), 512 threads = 8 waves x 80 cols. Unchanged from R10.
__global__ __launch_bounds__(512) void tail_mfma(
        const float* __restrict__ feat, const unsigned short* __restrict__ BgU,
        const unsigned short* __restrict__ BgX, const float* __restrict__ bp5,
        const unsigned short* __restrict__ hb, const unsigned short* __restrict__ cb,
        float* __restrict__ out) {
    __shared__ unsigned short xb[31 * 136];
    __shared__ unsigned short hcH[63 * 136];
    __shared__ unsigned short hcC[63 * 136];
    __shared__ unsigned short Lg[16 * 660];

    const int tid = threadIdx.x;
    const int l = blockIdx.x >> 7, tree = blockIdx.x & 127;
    const int lane = tid & 63, w = tid >> 6;
    const int quad = lane >> 4, l15 = lane & 15;
    const unsigned short* BU = BgU + (size_t)l * 512 * 128;
    const unsigned short* BX = BgX + (size_t)l * 512 * 128;
    const unsigned short* h = hb + (size_t)l * NN * 128;
    const unsigned short* c = cb + (size_t)l * NN * 128;
    const float* bb = bp5 + (size_t)l * 640;

    short8 bfU[5][4], bfX[5][4];
#pragma unroll
    for (int ni = 0; ni < 5; ni++) {
        int gc0 = w * 80 + ni * 16;
        int col = (gc0 < 512) ? gc0 : gc0 - 128;   // f1 cols alias Uf/Wf at col-128
#pragma unroll
        for (int kbl = 0; kbl < 4; kbl++) {
            bfU[ni][kbl] = *(const short8*)(BU + (size_t)(col + l15) * 128 + kbl * 32 + quad * 8);
            bfX[ni][kbl] = *(const short8*)(BX + (size_t)(col + l15) * 128 + kbl * 32 + quad * 8);
        }
    }
    {
        int row = tid >> 4, c8 = (tid & 15) * 8;
        if (row < 31) {
            const float* src = feat + ((size_t)tree * TS + row) * 128 + c8;
            short8 r;
#pragma unroll
            for (int e = 0; e < 8; e++) r[e] = (short)f2b(src[e]);
            *(short8*)(xb + row * 136 + c8) = r;
        }
        *(short8*)(hcH + (31 + row) * 136 + c8) =
            *(const short8*)(h + ((size_t)tree * TS + 31 + row) * 128 + c8);
        *(short8*)(hcC + (31 + row) * 136 + c8) =
            *(const short8*)(c + ((size_t)tree * TS + 31 + row) * 128 + c8);
    }
    __syncthreads();

    for (int dd = 4; dd >= 0; dd--) {
        const int nd = 1 << dd;
        const int rowA = (l15 < nd) ? l15 : nd - 1;   // clamp: extra rows unused
        const int heap = nd - 1 + rowA;
        floatx4 acc[5];
#pragma unroll
        for (int ni = 0; ni < 5; ni++) acc[ni] = (floatx4){0.f, 0.f, 0.f, 0.f};
#pragma unroll
        for (int kbl = 0; kbl < 4; kbl++) {
            int ko = kbl * 32 + quad * 8;
            short8 ax = *(const short8*)(xb + heap * 136 + ko);
            short8 h0 = *(const short8*)(hcH + (2 * heap + 1) * 136 + ko);
            short8 h1 = *(const short8*)(hcH + (2 * heap + 2) * 136 + ko);
            short8 hs;
#pragma unroll
            for (int e = 0; e < 8; e++)
                hs[e] = (short)f2b(b2f_u((unsigned short)h0[e]) +
                                   b2f_u((unsigned short)h1[e]));
#pragma unroll
            for (int ni = 0; ni < 5; ni++) {
                int gc0 = w * 80 + ni * 16;
                short8 a = (gc0 < 384) ? hs : ((gc0 < 512) ? h0 : h1);
                acc[ni] = __builtin_amdgcn_mfma_f32_16x16x32_bf16(ax, bfX[ni][kbl],
                                                                  acc[ni], 0, 0, 0);
                acc[ni] = __builtin_amdgcn_mfma_f32_16x16x32_bf16(a, bfU[ni][kbl],
                                                                  acc[ni], 0, 0, 0);
            }
        }
#pragma unroll
        for (int ni = 0; ni < 5; ni++)
#pragma unroll
            for (int r = 0; r < 4; r++)
                Lg[(quad * 4 + r) * 660 + w * 80 + ni * 16 + l15] = f2b(acc[ni][r]);
        __syncthreads();
        for (int idx = tid; idx < nd * 128; idx += 512) {
            int node = idx >> 7, t = idx & 127;
            int hp = nd - 1 + node;
            const unsigned short* Lr = Lg + node * 660;
            float iv = sig_(b2f_u(Lr[t]) + bb[t]);
            float ov = sig_(b2f_u(Lr[128 + t]) + bb[128 + t]);
            float uv = tanh_(b2f_u(Lr[256 + t]) + bb[256 + t]);
            float f0 = sig_(b2f_u(Lr[384 + t]) + bb[384 + t]);
            float f1 = sig_(b2f_u(Lr[512 + t]) + bb[512 + t]);
            float c0v = b2f_u(hcC[(2 * hp + 1) * 136 + t]);
            float c1v = b2f_u(hcC[(2 * hp + 2) * 136 + t]);
            float cn = iv * uv + f0 * c0v + f1 * c1v;
            float hn = ov * tanh_(cn);
            hcH[hp * 136 + t] = f2b(hn);
            hcC[hp * 136 + t] = f2b(cn);
            if (dd == 0) {
                out[((size_t)l * 128 + tree) * 128 + t] = hn;
                out[32768 + ((size_t)l * 128 + tree) * 128 + t] = cn;
            }
        }
        __syncthreads();
    }
}

extern "C" void kernel_launch(void* const* d_in, const int* in_sizes, int n_in,
                              void* d_out, int out_size, void* d_ws, size_t ws_size,
                              hipStream_t stream) {
    const float* feat = (const float*)d_in[0];
    const float* Wiou = (const float*)d_in[1];
    const float* biou = (const float*)d_in[2];
    const float* Uiou = (const float*)d_in[3];
    const float* Wf   = (const float*)d_in[4];
    const float* bfv  = (const float*)d_in[5];
    const float* Uf   = (const float*)d_in[6];
    float* out = (float*)d_out;

    // ws (bf16 shorts unless noted): h[2][NN*128] c[2][NN*128] Bg2[491520]
    //   BgU[131072] BgX[131072] bp5(f32)[1280]   total ~68.5 MB
    unsigned short* hb  = (unsigned short*)d_ws;
    unsigned short* cb  = hb + (size_t)2 * NN * 128;
    unsigned short* Bg  = cb + (size_t)2 * NN * 128;
    unsigned short* BgU = Bg + (size_t)491520;
    unsigned short* BgX = BgU + (size_t)131072;
    float* bp5 = (float*)(BgX + (size_t)131072);

    pack_b<<<2944, 256, 0, stream>>>(Wiou, biou, Uiou, Wf, bfv, Uf, Bg, BgU, BgX, bp5);

    // both layers in every dispatch
    gemm_level<4, 384, true><<<1024, 512, 0, stream>>>(feat, Bg, bp5, hb, cb, 0, 9);
    gemm_level<12, 640, false><<<512, 512, 0, stream>>>(feat, Bg, bp5, hb, cb, 7, 8);
    gemm_level<12, 640, false><<<256, 512, 0, stream>>>(feat, Bg, bp5, hb, cb, 6, 7);
    gemm_level<12, 640, false><<<128, 512, 0, stream>>>(feat, Bg, bp5, hb, cb, 5, 6);
    tail_mfma<<<256, 512, 0, stream>>>(feat, BgU, BgX, bp5, hb, cb, out);
}

// Round 12
// 238.303 us; speedup vs baseline: 2.0080x; 1.0502x over previous
//
#include <hip/hip_runtime.h>
#include <hip/hip_bf16.h>

// TreeLSTM on MI355X — MFMA formulation, round 12.
// 128 trees, heap layout, TREE_SIZE=511, depth 9; children of heap h: 2h+1, 2h+2.
// Gates GEMM: A-row = [x | h0 | h1] (K=384; Ui in both h-ranges via linearity)
//   @ B (384x640), col blocks [i|o|u|f0|f1].
// NEW: zero-LDS gemm levels — B-fragments load straight from global (L2-resident,
//   fragment-shaped layout), A-fragments straight from bf16 node rows (x pre-converted
//   to xb16 in pack). No barriers, no LDS staging, register epilogue (gate-aligned
//   tiles: lane owns all 5 gates of its output feature). Both layers per dispatch.
// Chain: pack(+xconv) -> leaf -> d7 -> d6 -> d5 -> tail. 6 dispatches.

#define TS 511
#define NT 128
#define NN (NT * TS)   // 65408

typedef __attribute__((ext_vector_type(8))) short short8;
typedef __attribute__((ext_vector_type(4))) float floatx4;

__device__ __forceinline__ unsigned short f2b(float f) {
    return __builtin_bit_cast(unsigned short, __float2bfloat16(f));
}
__device__ __forceinline__ float b2f_u(unsigned short u) {
    unsigned v = (unsigned)u << 16;
    return __builtin_bit_cast(float, v);
}
__device__ __forceinline__ float sig_(float x) { return 1.0f / (1.0f + __expf(-x)); }
__device__ __forceinline__ float tanh_(float x) {
    float a = fabsf(x);
    float t = __expf(-2.0f * a);
    float r = (1.0f - t) / (1.0f + t);
    return copysignf(r, x);
}

// ---------------- weight packing + x conversion ----------------
// Bg2[((l*12+kb)*640 + n)*32 + kp]: K=384. kb0-3: x (Wi/Wf/Wf). kb4-7: h0 (Ui/Uf/0).
//   kb8-11: h1 (Ui/0/Uf).
// BgU/BgX[(l*512+col)*128+kp]: tail col-major U/X parts.
// bp5[(l*5+g)*128+o]: biases. xb16[node*128+k]: feat converted to bf16.
__global__ void pack_b(const float* __restrict__ Wiou, const float* __restrict__ biou,
                       const float* __restrict__ Uiou, const float* __restrict__ Wf,
                       const float* __restrict__ bfv, const float* __restrict__ Uf,
                       const float* __restrict__ feat,
                       unsigned short* __restrict__ Bg, unsigned short* __restrict__ BgU,
                       unsigned short* __restrict__ BgX, float* __restrict__ bp5,
                       unsigned short* __restrict__ xb) {
    int tid = blockIdx.x * 256 + threadIdx.x;   // 0..1800191
    if (tid < 1280) {
        int l = tid / 640, r = tid % 640, g = r >> 7, o = r & 127;
        bp5[tid] = (g < 3) ? biou[l * 384 + r] : bfv[l * 128 + o];
    }
    if (tid < 491520) {
        int l = tid / 245760;
        int r = tid % 245760;
        int kb = r / 20480;
        int r2 = r % 20480;
        int n = r2 >> 5, kp = r2 & 31;
        int g = n >> 7, o = n & 127;
        float v = 0.f;
        if (kb < 4) {
            int k = kb * 32 + kp;
            v = (g < 3) ? Wiou[(l * 384 + g * 128 + o) * 128 + k]
                        : Wf[(l * 128 + o) * 128 + k];
        } else if (kb < 8) {
            int k = (kb - 4) * 32 + kp;
            if (g < 3)       v = Uiou[(l * 384 + g * 128 + o) * 128 + k];
            else if (g == 3) v = Uf[(l * 128 + o) * 128 + k];
        } else {
            int k = (kb - 8) * 32 + kp;
            if (g < 3)       v = Uiou[(l * 384 + g * 128 + o) * 128 + k];
            else if (g == 4) v = Uf[(l * 128 + o) * 128 + k];
        }
        Bg[tid] = f2b(v);
    } else if (tid < 622592) {
        int e2 = tid - 491520;                 // U-part, < 131072
        int l = e2 >> 16, r = e2 & 65535, col = r >> 7, kp = r & 127;
        float v = (col < 384) ? Uiou[(l * 384 + col) * 128 + kp]
                              : Uf[(l * 128 + (col - 384)) * 128 + kp];
        BgU[((size_t)(l * 512 + col)) * 128 + kp] = f2b(v);
    } else if (tid < 753664) {
        int e2 = tid - 622592;                 // X-part, < 131072
        int l = e2 >> 16, r = e2 & 65535, col = r >> 7, kp = r & 127;
        float v = (col < 384) ? Wiou[(l * 384 + col) * 128 + kp]
                              : Wf[(l * 128 + (col - 384)) * 128 + kp];
        BgX[((size_t)(l * 512 + col)) * 128 + kp] = f2b(v);
    } else {
        int e = tid - 753664;                  // x conversion, < 1046528 (8 elems each)
        size_t base = (size_t)e * 8;
        float4 v0 = *(const float4*)(feat + base);
        float4 v1 = *(const float4*)(feat + base + 4);
        short8 r;
        r[0] = (short)f2b(v0.x); r[1] = (short)f2b(v0.y);
        r[2] = (short)f2b(v0.z); r[3] = (short)f2b(v0.w);
        r[4] = (short)f2b(v1.x); r[5] = (short)f2b(v1.y);
        r[6] = (short)f2b(v1.z); r[7] = (short)f2b(v1.w);
        *(short8*)(xb + base) = r;
    }
}

// ---------------- zero-LDS MFMA level GEMM (d=8..5) ----------------
// 256 threads = 4 waves. Wave W = blockIdx.x*4+wave: wn = W&3 (col group),
// mt = W>>2 -> (layer, 32-node m-tile). Wave computes 32 nodes x its gate-aligned
// tiles ni = g*2+ch at col g*128 + wn*32 + ch*16. All operands direct from global.
template <int NKB, int NI, bool LEAF>
__global__ __launch_bounds__(256) void gemm_level(
        const unsigned short* __restrict__ xb, const unsigned short* __restrict__ Bg,
        const float* __restrict__ bp5, unsigned short* __restrict__ hb,
        unsigned short* __restrict__ cb, int d, int mshift) {
    const int tid = threadIdx.x;
    const int lane = tid & 63, wave = tid >> 6;
    const int W = blockIdx.x * 4 + wave;
    const int wn = W & 3;
    const int mt = W >> 2;
    const int l = mt >> mshift;
    const int m = mt & ((1 << mshift) - 1);
    const int quad = lane >> 4, l15 = lane & 15;
    unsigned short* h = hb + (size_t)l * NN * 128;
    unsigned short* c = cb + (size_t)l * NN * 128;

    // per-lane A-row node indices (row = l15) for the two 16-node subtiles
    int nodeA[2], ch0A[2];
#pragma unroll
    for (int mi = 0; mi < 2; mi++) {
        int j = m * 32 + mi * 16 + l15;
        if (LEAF) {
            nodeA[mi] = (j >> 8) * TS + 255 + (j & 255);
            ch0A[mi] = 0;
        } else {
            int tree = j >> d, idx = j & ((1 << d) - 1);
            int heap = (1 << d) - 1 + idx;
            nodeA[mi] = tree * TS + heap;
            ch0A[mi] = tree * TS + 2 * heap + 1;
        }
    }

    floatx4 acc[2][NI];
#pragma unroll
    for (int mi = 0; mi < 2; mi++)
#pragma unroll
        for (int ni = 0; ni < NI; ni++)
            acc[mi][ni] = (floatx4){0.f, 0.f, 0.f, 0.f};

#pragma unroll
    for (int kb = 0; kb < NKB; kb++) {
        short8 bf[NI];
#pragma unroll
        for (int ni = 0; ni < NI; ni++) {
            const int g = ni >> 1;
            if (!LEAF) {   // structural-zero tiles (compile-time folded)
                if (g == 3 && kb >= 8) continue;
                if (g == 4 && kb >= 4 && kb < 8) continue;
            }
            int col = g * 128 + wn * 32 + (ni & 1) * 16 + l15;
            bf[ni] = *(const short8*)(Bg + ((size_t)(l * 12 + kb) * 640 + col) * 32 + quad * 8);
        }
#pragma unroll
        for (int mi = 0; mi < 2; mi++) {
            const unsigned short* asrc;
            if (LEAF || kb < 4)      asrc = xb + (size_t)nodeA[mi] * 128 + kb * 32;
            else if (kb < 8)         asrc = h + (size_t)ch0A[mi] * 128 + (kb - 4) * 32;
            else                     asrc = h + (size_t)(ch0A[mi] + 1) * 128 + (kb - 8) * 32;
            short8 a = *(const short8*)(asrc + quad * 8);
#pragma unroll
            for (int ni = 0; ni < NI; ni++) {
                const int g = ni >> 1;
                if (!LEAF) {
                    if (g == 3 && kb >= 8) continue;
                    if (g == 4 && kb >= 4 && kb < 8) continue;
                }
                acc[mi][ni] = __builtin_amdgcn_mfma_f32_16x16x32_bf16(a, bf[ni],
                                                                      acc[mi][ni], 0, 0, 0);
            }
        }
    }

    // -------- register epilogue: lane owns gates of features o = wn*32+ch*16+l15
    float bbv[NI];
#pragma unroll
    for (int ni = 0; ni < NI; ni++)
        bbv[ni] = bp5[l * 640 + (ni >> 1) * 128 + wn * 32 + (ni & 1) * 16 + l15];

#pragma unroll
    for (int mi = 0; mi < 2; mi++) {
        int nodes[4];
        unsigned short c0v[4][2], c1v[4][2];
#pragma unroll
        for (int r = 0; r < 4; r++) {
            int j = m * 32 + mi * 16 + quad * 4 + r;
            if (LEAF) {
                nodes[r] = (j >> 8) * TS + 255 + (j & 255);
            } else {
                int tree = j >> d, idx = j & ((1 << d) - 1);
                int heap = (1 << d) - 1 + idx;
                nodes[r] = tree * TS + heap;
                int ch0 = tree * TS + 2 * heap + 1;
#pragma unroll
                for (int ch = 0; ch < 2; ch++) {
                    int o = wn * 32 + ch * 16 + l15;
                    c0v[r][ch] = c[(size_t)ch0 * 128 + o];
                    c1v[r][ch] = c[(size_t)(ch0 + 1) * 128 + o];
                }
            }
        }
#pragma unroll
        for (int r = 0; r < 4; r++) {
#pragma unroll
            for (int ch = 0; ch < 2; ch++) {
                int o = wn * 32 + ch * 16 + l15;
                float iv = sig_(acc[mi][0 + ch][r] + bbv[0 + ch]);
                float ov = sig_(acc[mi][2 + ch][r] + bbv[2 + ch]);
                float uv = tanh_(acc[mi][4 + ch][r] + bbv[4 + ch]);
                float cn;
                if (LEAF) {
                    cn = iv * uv;
                } else {
                    float f0 = sig_(acc[mi][6 + ch][r] + bbv[6 + ch]);
                    float f1 = sig_(acc[mi][8 + ch][r] + bbv[8 + ch]);
                    cn = iv * uv + f0 * b2f_u(c0v[r][ch]) + f1 * b2f_u(c1v[r][ch]);
                }
                float hn = ov * tanh_(cn);
                h[(size_t)nodes[r] * 128 + o] = f2b(hn);
                c[(size_t)nodes[r] * 128 + o] = f2b(cn);
            }
        }
    }
}

// ---------------- tail: d=4..0 + root out, fully register-resident B ----------------
// 256 blocks = (layer, tree), 512 threads = 8 waves x 80 cols. Unchanged from R11.
__global__ __launch_bounds__(512) void tail_mfma(
        const float* __restrict__ feat, const unsigned short* __restrict__ BgU,
        const unsigned short* __restrict__ BgX, const float* __restrict__ bp5,
        const unsigned short* __restrict__ hb, const unsigned short* __restrict__ cb,
        float* __restrict__ out) {
    __shared__ unsigned short xb[31 * 136];
    __shared__ unsigned short hcH[63 * 136];
    __shared__ unsigned short hcC[63 * 136];
    __shared__ unsigned short Lg[16 * 660];

    const int tid = threadIdx.x;
    const int l = blockIdx.x >> 7, tree = blockIdx.x & 127;
    const int lane = tid & 63, w = tid >> 6;
    const int quad = lane >> 4, l15 = lane & 15;
    const unsigned short* BU = BgU + (size_t)l * 512 * 128;
    const unsigned short* BX = BgX + (size_t)l * 512 * 128;
    const unsigned short* h = hb + (size_t)l * NN * 128;
    const unsigned short* c = cb + (size_t)l * NN * 128;
    const float* bb = bp5 + (size_t)l * 640;

    short8 bfU[5][4], bfX[5][4];
#pragma unroll
    for (int ni = 0; ni < 5; ni++) {
        int gc0 = w * 80 + ni * 16;
        int col = (gc0 < 512) ? gc0 : gc0 - 128;   // f1 cols alias Uf/Wf at col-128
#pragma unroll
        for (int kbl = 0; kbl < 4; kbl++) {
            bfU[ni][kbl] = *(const short8*)(BU + (size_t)(col + l15) * 128 + kbl * 32 + quad * 8);
            bfX[ni][kbl] = *(const short8*)(BX + (size_t)(col + l15) * 128 + kbl * 32 + quad * 8);
        }
    }
    {
        int row = tid >> 4, c8 = (tid & 15) * 8;
        if (row < 31) {
            const float* src = feat + ((size_t)tree * TS + row) * 128 + c8;
            short8 r;
#pragma unroll
            for (int e = 0; e < 8; e++) r[e] = (short)f2b(src[e]);
            *(short8*)(xb + row * 136 + c8) = r;
        }
        *(short8*)(hcH + (31 + row) * 136 + c8) =
            *(const short8*)(h + ((size_t)tree * TS + 31 + row) * 128 + c8);
        *(short8*)(hcC + (31 + row) * 136 + c8) =
            *(const short8*)(c + ((size_t)tree * TS + 31 + row) * 128 + c8);
    }
    __syncthreads();

    for (int dd = 4; dd >= 0; dd--) {
        const int nd = 1 << dd;
        const int rowA = (l15 < nd) ? l15 : nd - 1;   // clamp: extra rows unused
        const int heap = nd - 1 + rowA;
        floatx4 acc[5];
#pragma unroll
        for (int ni = 0; ni < 5; ni++) acc[ni] = (floatx4){0.f, 0.f, 0.f, 0.f};
#pragma unroll
        for (int kbl = 0; kbl < 4; kbl++) {
            int ko = kbl * 32 + quad * 8;
            short8 ax = *(const short8*)(xb + heap * 136 + ko);
            short8 h0 = *(const short8*)(hcH + (2 * heap + 1) * 136 + ko);
            short8 h1 = *(const short8*)(hcH + (2 * heap + 2) * 136 + ko);
            short8 hs;
#pragma unroll
            for (int e = 0; e < 8; e++)
                hs[e] = (short)f2b(b2f_u((unsigned short)h0[e]) +
                                   b2f_u((unsigned short)h1[e]));
#pragma unroll
            for (int ni = 0; ni < 5; ni++) {
                int gc0 = w * 80 + ni * 16;
                short8 a = (gc0 < 384) ? hs : ((gc0 < 512) ? h0 : h1);
                acc[ni] = __builtin_amdgcn_mfma_f32_16x16x32_bf16(ax, bfX[ni][kbl],
                                                                  acc[ni], 0, 0, 0);
                acc[ni] = __builtin_amdgcn_mfma_f32_16x16x32_bf16(a, bfU[ni][kbl],
                                                                  acc[ni], 0, 0, 0);
            }
        }
#pragma unroll
        for (int ni = 0; ni < 5; ni++)
#pragma unroll
            for (int r = 0; r < 4; r++)
                Lg[(quad * 4 + r) * 660 + w * 80 + ni * 16 + l15] = f2b(acc[ni][r]);
        __syncthreads();
        for (int idx = tid; idx < nd * 128; idx += 512) {
            int node = idx >> 7, t = idx & 127;
            int hp = nd - 1 + node;
            const unsigned short* Lr = Lg + node * 660;
            float iv = sig_(b2f_u(Lr[t]) + bb[t]);
            float ov = sig_(b2f_u(Lr[128 + t]) + bb[128 + t]);
            float uv = tanh_(b2f_u(Lr[256 + t]) + bb[256 + t]);
            float f0 = sig_(b2f_u(Lr[384 + t]) + bb[384 + t]);
            float f1 = sig_(b2f_u(Lr[512 + t]) + bb[512 + t]);
            float c0v = b2f_u(hcC[(2 * hp + 1) * 136 + t]);
            float c1v = b2f_u(hcC[(2 * hp + 2) * 136 + t]);
            float cn = iv * uv + f0 * c0v + f1 * c1v;
            float hn = ov * tanh_(cn);
            hcH[hp * 136 + t] = f2b(hn);
            hcC[hp * 136 + t] = f2b(cn);
            if (dd == 0) {
                out[((size_t)l * 128 + tree) * 128 + t] = hn;
                out[32768 + ((size_t)l * 128 + tree) * 128 + t] = cn;
            }
        }
        __syncthreads();
    }
}

extern "C" void kernel_launch(void* const* d_in, const int* in_sizes, int n_in,
                              void* d_out, int out_size, void* d_ws, size_t ws_size,
                              hipStream_t stream) {
    const float* feat = (const float*)d_in[0];
    const float* Wiou = (const float*)d_in[1];
    const float* biou = (const float*)d_in[2];
    const float* Uiou = (const float*)d_in[3];
    const float* Wf   = (const float*)d_in[4];
    const float* bfv  = (const float*)d_in[5];
    const float* Uf   = (const float*)d_in[6];
    float* out = (float*)d_out;

    // ws (bf16 shorts unless noted): h[2][NN*128] c[2][NN*128] Bg2[491520]
    //   BgU[131072] BgX[131072] xb16[NN*128] bp5(f32)[1280]   total ~85 MB (ws ~268 MB)
    unsigned short* hb  = (unsigned short*)d_ws;
    unsigned short* cb  = hb + (size_t)2 * NN * 128;
    unsigned short* Bg  = cb + (size_t)2 * NN * 128;
    unsigned short* BgU = Bg + (size_t)491520;
    unsigned short* BgX = BgU + (size_t)131072;
    unsigned short* xb16 = BgX + (size_t)131072;
    float* bp5 = (float*)(xb16 + (size_t)NN * 128);

    pack_b<<<7032, 256, 0, stream>>>(Wiou, biou, Uiou, Wf, bfv, Uf, feat,
                                     Bg, BgU, BgX, bp5, xb16);

    // both layers in every dispatch; zero-LDS streaming GEMMs
    gemm_level<4, 6, true><<<2048, 256, 0, stream>>>(xb16, Bg, bp5, hb, cb, 0, 10);
    gemm_level<12, 10, false><<<1024, 256, 0, stream>>>(xb16, Bg, bp5, hb, cb, 7, 9);
    gemm_level<12, 10, false><<<512, 256, 0, stream>>>(xb16, Bg, bp5, hb, cb, 6, 8);
    gemm_level<12, 10, false><<<256, 256, 0, stream>>>(xb16, Bg, bp5, hb, cb, 5, 7);
    tail_mfma<<<256, 512, 0, stream>>>(feat, BgU, BgX, bp5, hb, cb, out);
}